// Round 1
// baseline (30.275 us; speedup 1.0000x reference)
//
#include <hip/hip_runtime.h>
#include <math.h>

namespace {
constexpr int R_RUNS   = 4096;
constexpr int T_STEPS  = 2048;
constexpr int XDIM     = 8;
constexpr int ZDIM     = 8;
constexpr int K_CHUNKS = 64;                 // chunks per run
constexpr int L_CHUNK  = T_STEPS / K_CHUNKS; // 32 timesteps per chunk
constexpr int NG       = R_RUNS / 64;        // 64 run-groups of 64 runs (one wave each)
constexpr int PAD_W    = L_CHUNK + 3;        // 35 -> bank index (3*lane + j) % 32, 2-way = free
}

__device__ __forceinline__ float sigmoidf_(float x) {
    return 1.0f / (1.0f + expf(-x));
}

// ---------------------------------------------------------------------------
// K1: per-(run, chunk) scan summaries.
// Chunk k over elements e_t = (G_hat, c_t), c_t = b_{t-1}, c_0 = 0.
// Summary u = sum_{j=0}^{L-1} G^{L-1-j} c_{t0+j}, so theta_end(k) = G^L * theta_end(k-1) + u.
// Wave = 64 runs (lane = run), so Z row addresses are wave-uniform -> s_load broadcast.
// ---------------------------------------------------------------------------
extern "C" __global__ __launch_bounds__(256, 4)
void dlm_k1_summary(const float* __restrict__ Zt, const float* __restrict__ G,
                    const float* __restrict__ gamma, float* __restrict__ U)
{
    const int wid  = __builtin_amdgcn_readfirstlane((int)(threadIdx.x >> 6));
    const int lane = threadIdx.x & 63;
    const int wave = blockIdx.x * 4 + wid;
    const int g = wave & (NG - 1);   // run group
    const int k = wave / NG;         // chunk index
    const int r = (g << 6) + lane;

    const float4 g0 = *reinterpret_cast<const float4*>(gamma + (size_t)r * ZDIM);
    const float4 g1 = *reinterpret_cast<const float4*>(gamma + (size_t)r * ZDIM + 4);
    const float gm[8] = {g0.x, g0.y, g0.z, g0.w, g1.x, g1.y, g1.z, g1.w};

    const float gh = sigmoidf_(G[r]);
    const int t0 = k * L_CHUNK;

    float b_prev = 0.0f;
    if (k > 0) {
        const float* __restrict__ z = Zt + (size_t)(t0 - 1) * ZDIM;
        float s = 0.0f;
        #pragma unroll
        for (int i = 0; i < ZDIM; ++i) s = fmaf(z[i], gm[i], s);
        b_prev = s;
    }

    float u = 0.0f;
    #pragma unroll 4
    for (int j = 0; j < L_CHUNK; ++j) {
        const float* __restrict__ z = Zt + (size_t)(t0 + j) * ZDIM;
        u = fmaf(gh, u, b_prev);                    // u = G*u + c_t  (c_t = b_{t-1})
        float s = 0.0f;
        #pragma unroll
        for (int i = 0; i < ZDIM; ++i) s = fmaf(z[i], gm[i], s);
        b_prev = s;                                  // b_t = Z_t . gamma_r
    }

    U[(size_t)k * R_RUNS + r] = u;
}

// ---------------------------------------------------------------------------
// K2: tiny per-run exclusive prefix scan over the K chunk summaries.
// P[k][r] = theta at (t0-1) for chunk k.  theta_end(-1) = 0.
// ---------------------------------------------------------------------------
extern "C" __global__ __launch_bounds__(256)
void dlm_k2_scan(const float* __restrict__ G, const float* __restrict__ U,
                 float* __restrict__ P)
{
    const int r = blockIdx.x * blockDim.x + threadIdx.x;
    if (r >= R_RUNS) return;
    const float gh = sigmoidf_(G[r]);
    float A = gh;
    #pragma unroll
    for (int i = 0; i < 5; ++i) A = A * A;   // gh^32 == gh^L_CHUNK
    float th = 0.0f;
    for (int k = 0; k < K_CHUNKS; ++k) {
        P[(size_t)k * R_RUNS + r] = th;
        th = fmaf(A, th, U[(size_t)k * R_RUNS + r]);
    }
}

// ---------------------------------------------------------------------------
// K3: final outputs. Wave = 64 runs x one chunk of 32 timesteps.
// out[r][t] = theta_t + X_t.eta_r + Z_t.zeta_r, theta_t = G*theta_{t-1} + b_{t-1}.
// Results staged in a padded per-wave LDS tile, then flushed coalesced.
// ---------------------------------------------------------------------------
extern "C" __global__ __launch_bounds__(256, 4)
void dlm_k3_output(const float* __restrict__ Xt, const float* __restrict__ Zt,
                   const float* __restrict__ G, const float* __restrict__ eta,
                   const float* __restrict__ zeta, const float* __restrict__ gamma,
                   const float* __restrict__ P, float* __restrict__ out)
{
    __shared__ float tile[4][64][PAD_W];

    const int wid  = __builtin_amdgcn_readfirstlane((int)(threadIdx.x >> 6));
    const int lane = threadIdx.x & 63;
    const int wave = blockIdx.x * 4 + wid;
    const int g = wave & (NG - 1);
    const int k = wave / NG;
    const int r = (g << 6) + lane;

    const float4 e0 = *reinterpret_cast<const float4*>(eta   + (size_t)r * XDIM);
    const float4 e1 = *reinterpret_cast<const float4*>(eta   + (size_t)r * XDIM + 4);
    const float4 z0 = *reinterpret_cast<const float4*>(zeta  + (size_t)r * ZDIM);
    const float4 z1 = *reinterpret_cast<const float4*>(zeta  + (size_t)r * ZDIM + 4);
    const float4 g0 = *reinterpret_cast<const float4*>(gamma + (size_t)r * ZDIM);
    const float4 g1 = *reinterpret_cast<const float4*>(gamma + (size_t)r * ZDIM + 4);
    const float et[8] = {e0.x, e0.y, e0.z, e0.w, e1.x, e1.y, e1.z, e1.w};
    const float zz[8] = {z0.x, z0.y, z0.z, z0.w, z1.x, z1.y, z1.z, z1.w};
    const float gm[8] = {g0.x, g0.y, g0.z, g0.w, g1.x, g1.y, g1.z, g1.w};

    const float gh = sigmoidf_(G[r]);
    float theta = P[(size_t)k * R_RUNS + r];
    const int t0 = k * L_CHUNK;

    float b_prev = 0.0f;
    if (k > 0) {
        const float* __restrict__ z = Zt + (size_t)(t0 - 1) * ZDIM;
        float s = 0.0f;
        #pragma unroll
        for (int i = 0; i < ZDIM; ++i) s = fmaf(z[i], gm[i], s);
        b_prev = s;
    }

    #pragma unroll 4
    for (int j = 0; j < L_CHUNK; ++j) {
        const int t = t0 + j;
        const float* __restrict__ x = Xt + (size_t)t * XDIM;   // wave-uniform -> s_load
        const float* __restrict__ z = Zt + (size_t)t * ZDIM;   // wave-uniform -> s_load
        float bx = 0.0f, bz = 0.0f, bb = 0.0f;
        #pragma unroll
        for (int i = 0; i < 8; ++i) {
            bx = fmaf(x[i], et[i], bx);
            bz = fmaf(z[i], zz[i], bz);
            bb = fmaf(z[i], gm[i], bb);
        }
        theta = fmaf(gh, theta, b_prev);
        tile[wid][lane][j] = theta + bx + bz;
        b_prev = bb;
    }

    __syncthreads();

    // Flush: 2 run-rows per instruction, 128B contiguous per 32-lane half.
    const int rr_half = lane >> 5;   // 0 or 1
    const int c       = lane & 31;   // timestep within chunk
    #pragma unroll
    for (int it = 0; it < 32; ++it) {
        const int rr = it * 2 + rr_half;
        const float v = tile[wid][rr][c];
        out[(size_t)((g << 6) + rr) * T_STEPS + t0 + c] = v;
    }
}

// ---------------------------------------------------------------------------
extern "C" void kernel_launch(void* const* d_in, const int* in_sizes, int n_in,
                              void* d_out, int out_size, void* d_ws, size_t ws_size,
                              hipStream_t stream)
{
    const float* Xt    = (const float*)d_in[0];
    const float* Zt    = (const float*)d_in[1];
    const float* G     = (const float*)d_in[2];
    const float* eta   = (const float*)d_in[3];
    const float* zeta  = (const float*)d_in[4];
    const float* gamma = (const float*)d_in[5];
    float* out = (float*)d_out;

    // workspace: U[K][R] and P[K][R], 1 MB each
    float* U = (float*)d_ws;
    float* P = U + (size_t)K_CHUNKS * R_RUNS;

    const dim3 blk(256);
    const int waves = NG * K_CHUNKS;          // 4096
    const dim3 grid13(waves / 4);             // 1024 blocks (4 waves each)
    const dim3 grid2(R_RUNS / 256);           // 16 blocks

    dlm_k1_summary<<<grid13, blk, 0, stream>>>(Zt, G, gamma, U);
    dlm_k2_scan   <<<grid2,  blk, 0, stream>>>(G, U, P);
    dlm_k3_output <<<grid13, blk, 0, stream>>>(Xt, Zt, G, eta, zeta, gamma, P, out);
}

// Round 2
// 29.331 us; speedup vs baseline: 1.0322x; 1.0322x over previous
//
#include <hip/hip_runtime.h>
#include <math.h>

namespace {
constexpr int R_RUNS   = 4096;
constexpr int T_STEPS  = 2048;
constexpr int XDIM     = 8;
constexpr int ZDIM     = 8;
constexpr int K_CHUNKS = 64;                 // chunks per run
constexpr int L_CHUNK  = T_STEPS / K_CHUNKS; // 32 timesteps per chunk
constexpr int NG       = R_RUNS / 64;        // 64 run-groups of 64 runs (one wave each)
constexpr int PAD_W    = L_CHUNK + 3;        // 35 -> bank index (3*lane + j) % 32, 2-way = free
}

__device__ __forceinline__ float sigmoidf_(float x) {
    return 1.0f / (1.0f + expf(-x));
}

// ---------------------------------------------------------------------------
// K1: per-(run, chunk) scan summaries.
// u_k = sum_{j=0}^{L-1} gh^{L-1-j} c_{t0+j},  c_t = b_{t-1},  b_t = Z_t . gamma_r
// so theta_end(k) = gh^L * theta_end(k-1) + u_k.
// Wave = 64 runs (lane = run); Z row addresses are wave-uniform -> scalar loads.
// ---------------------------------------------------------------------------
extern "C" __global__ __launch_bounds__(256, 4)
void dlm_k1_summary(const float* __restrict__ Zt, const float* __restrict__ G,
                    const float* __restrict__ gamma, float* __restrict__ U)
{
    const int wid  = __builtin_amdgcn_readfirstlane((int)(threadIdx.x >> 6));
    const int lane = threadIdx.x & 63;
    const int wave = blockIdx.x * 4 + wid;
    const int g = wave & (NG - 1);   // run group
    const int k = wave / NG;         // chunk index
    const int r = (g << 6) + lane;

    const float4 g0 = *reinterpret_cast<const float4*>(gamma + (size_t)r * ZDIM);
    const float4 g1 = *reinterpret_cast<const float4*>(gamma + (size_t)r * ZDIM + 4);
    const float gm[8] = {g0.x, g0.y, g0.z, g0.w, g1.x, g1.y, g1.z, g1.w};

    const float gh = sigmoidf_(G[r]);
    const int t0 = k * L_CHUNK;

    float b_prev = 0.0f;
    if (k > 0) {
        const float* __restrict__ z = Zt + (size_t)(t0 - 1) * ZDIM;
        float s = 0.0f;
        #pragma unroll
        for (int i = 0; i < ZDIM; ++i) s = fmaf(z[i], gm[i], s);
        b_prev = s;
    }

    float u = 0.0f;
    #pragma unroll 4
    for (int j = 0; j < L_CHUNK; ++j) {
        const float* __restrict__ z = Zt + (size_t)(t0 + j) * ZDIM;
        u = fmaf(gh, u, b_prev);                    // u = gh*u + c_t  (c_t = b_{t-1})
        float s = 0.0f;
        #pragma unroll
        for (int i = 0; i < ZDIM; ++i) s = fmaf(z[i], gm[i], s);
        b_prev = s;
    }

    U[(size_t)k * R_RUNS + r] = u;
}

// ---------------------------------------------------------------------------
// K3': fused chunk-prefix scan + output.
// Each wave (g,k): theta_start = scan of U[0..k-1][r] (coalesced, L2-hot),
// then replay the chunk with full output math; stage rows in padded LDS tile,
// flush coalesced.
// ---------------------------------------------------------------------------
extern "C" __global__ __launch_bounds__(256, 4)
void dlm_k3_output(const float* __restrict__ Xt, const float* __restrict__ Zt,
                   const float* __restrict__ G, const float* __restrict__ eta,
                   const float* __restrict__ zeta, const float* __restrict__ gamma,
                   const float* __restrict__ U, float* __restrict__ out)
{
    __shared__ float tile[4][64][PAD_W];

    const int wid  = __builtin_amdgcn_readfirstlane((int)(threadIdx.x >> 6));
    const int lane = threadIdx.x & 63;
    const int wave = blockIdx.x * 4 + wid;
    const int g = wave & (NG - 1);
    const int k = wave / NG;
    const int r = (g << 6) + lane;

    const float4 e0 = *reinterpret_cast<const float4*>(eta   + (size_t)r * XDIM);
    const float4 e1 = *reinterpret_cast<const float4*>(eta   + (size_t)r * XDIM + 4);
    const float4 z0 = *reinterpret_cast<const float4*>(zeta  + (size_t)r * ZDIM);
    const float4 z1 = *reinterpret_cast<const float4*>(zeta  + (size_t)r * ZDIM + 4);
    const float4 g0 = *reinterpret_cast<const float4*>(gamma + (size_t)r * ZDIM);
    const float4 g1 = *reinterpret_cast<const float4*>(gamma + (size_t)r * ZDIM + 4);
    const float et[8] = {e0.x, e0.y, e0.z, e0.w, e1.x, e1.y, e1.z, e1.w};
    const float zz[8] = {z0.x, z0.y, z0.z, z0.w, z1.x, z1.y, z1.z, z1.w};
    const float gm[8] = {g0.x, g0.y, g0.z, g0.w, g1.x, g1.y, g1.z, g1.w};

    const float gh = sigmoidf_(G[r]);
    const int t0 = k * L_CHUNK;

    // ---- theta at t0-1: scan chunk summaries U[0..k-1][r] ----
    float A = gh;
    #pragma unroll
    for (int i = 0; i < 5; ++i) A = A * A;   // gh^32 == gh^L_CHUNK
    float theta = 0.0f;
    for (int j = 0; j < k; ++j)
        theta = fmaf(A, theta, U[(size_t)j * R_RUNS + r]);

    // ---- b at t0-1 ----
    float b_prev = 0.0f;
    if (k > 0) {
        const float* __restrict__ z = Zt + (size_t)(t0 - 1) * ZDIM;
        float s = 0.0f;
        #pragma unroll
        for (int i = 0; i < ZDIM; ++i) s = fmaf(z[i], gm[i], s);
        b_prev = s;
    }

    // ---- replay chunk with output math ----
    #pragma unroll 4
    for (int j = 0; j < L_CHUNK; ++j) {
        const int t = t0 + j;
        const float* __restrict__ x = Xt + (size_t)t * XDIM;   // wave-uniform -> s_load
        const float* __restrict__ z = Zt + (size_t)t * ZDIM;   // wave-uniform -> s_load
        float bx = 0.0f, bz = 0.0f, bb = 0.0f;
        #pragma unroll
        for (int i = 0; i < 8; ++i) {
            bx = fmaf(x[i], et[i], bx);
            bz = fmaf(z[i], zz[i], bz);
            bb = fmaf(z[i], gm[i], bb);
        }
        theta = fmaf(gh, theta, b_prev);
        tile[wid][lane][j] = theta + bx + bz;
        b_prev = bb;
    }

    __syncthreads();

    // Flush: 2 run-rows per instruction, 128B contiguous per 32-lane half.
    const int rr_half = lane >> 5;   // 0 or 1
    const int c       = lane & 31;   // timestep within chunk
    #pragma unroll
    for (int it = 0; it < 32; ++it) {
        const int rr = it * 2 + rr_half;
        const float v = tile[wid][rr][c];
        out[(size_t)((g << 6) + rr) * T_STEPS + t0 + c] = v;
    }
}

// ---------------------------------------------------------------------------
extern "C" void kernel_launch(void* const* d_in, const int* in_sizes, int n_in,
                              void* d_out, int out_size, void* d_ws, size_t ws_size,
                              hipStream_t stream)
{
    const float* Xt    = (const float*)d_in[0];
    const float* Zt    = (const float*)d_in[1];
    const float* G     = (const float*)d_in[2];
    const float* eta   = (const float*)d_in[3];
    const float* zeta  = (const float*)d_in[4];
    const float* gamma = (const float*)d_in[5];
    float* out = (float*)d_out;

    float* U = (float*)d_ws;                  // U[K][R], 1 MB

    const dim3 blk(256);
    const int waves = NG * K_CHUNKS;          // 4096
    const dim3 grid(waves / 4);               // 1024 blocks (4 waves each)

    dlm_k1_summary<<<grid, blk, 0, stream>>>(Zt, G, gamma, U);
    dlm_k3_output <<<grid, blk, 0, stream>>>(Xt, Zt, G, eta, zeta, gamma, U, out);
}